// Round 1
// baseline (724.795 us; speedup 1.0000x reference)
//
#include <hip/hip_runtime.h>
#include <stdint.h>
#include <stddef.h>

// Problem constants (ExpertsChooseMaskedContract)
#define B_  4
#define T_  4096
#define I_  1024
#define E_  8
#define C_  512
#define O_  1024
#define EC_ (E_*C_)   // 4096

typedef __attribute__((ext_vector_type(8))) short bf16x8;   // 8 bf16 = 4 VGPR (guide §3)
typedef __attribute__((ext_vector_type(4))) float f32x4;    // MFMA C/D
typedef __attribute__((ext_vector_type(4))) unsigned short us4;

// fp32 -> bf16 round-to-nearest-even (inputs finite; no NaN handling needed)
__device__ __forceinline__ unsigned short f2bf(float f) {
  unsigned u = __builtin_bit_cast(unsigned, f);
  u += 0x7FFFu + ((u >> 16) & 1u);
  return (unsigned short)(u >> 16);
}

// async global->LDS, 16B per lane. LDS dest must be wave-uniform base (HW adds lane*16).
__device__ __forceinline__ void async16(const unsigned short* g, unsigned short* l) {
  __builtin_amdgcn_global_load_lds((const __attribute__((address_space(1))) void*)g,
                                   (__attribute__((address_space(3))) void*)l, 16, 0, 0);
}

// ---------------------------------------------------------------------------
// Transpose + cast: in[b][R][CC] f32  ->  out[b][CC][R] bf16.  64x64 tiles.
// ---------------------------------------------------------------------------
template<int R, int CC>
__global__ __launch_bounds__(256) void tcast_kernel(const float* __restrict__ in,
                                                    unsigned short* __restrict__ out) {
  __shared__ float ls[64][68];   // +4 pad keeps float4 writes 16B-aligned
  const int tilesPerB = (R/64)*(CC/64);
  const int bx = blockIdx.x;
  const int b  = bx / tilesPerB;
  const int t  = bx % tilesPerB;
  const int tr = t / (CC/64);
  const int tc = t % (CC/64);
  const float* ib = in + (size_t)b * R * CC;
  unsigned short* ob = out + (size_t)b * R * CC;
  const int tid = threadIdx.x;
  const int rr  = tid >> 4;          // 0..15
  const int c4  = (tid & 15) * 4;    // 0..60
  #pragma unroll
  for (int p = 0; p < 4; ++p) {
    const int r = p * 16 + rr;
    float4 v = *(const float4*)&ib[(size_t)(tr*64 + r) * CC + tc*64 + c4];
    *(float4*)&ls[r][c4] = v;
  }
  __syncthreads();
  #pragma unroll
  for (int p = 0; p < 4; ++p) {
    const int c = p * 16 + rr;       // column of input = row of output
    us4 o;
    o.x = f2bf(ls[c4+0][c]);
    o.y = f2bf(ls[c4+1][c]);
    o.z = f2bf(ls[c4+2][c]);
    o.w = f2bf(ls[c4+3][c]);
    *(us4*)&ob[(size_t)(tc*64 + c) * R + tr*64 + c4] = o;
  }
}

// ---------------------------------------------------------------------------
// Elementwise cast: weight f32 -> bf16 (layout unchanged [E][O][I], K-contig).
// ---------------------------------------------------------------------------
__global__ __launch_bounds__(256) void wcvt_kernel(const float* __restrict__ in,
                                                   unsigned short* __restrict__ out, int n4) {
  const int i = blockIdx.x * 256 + threadIdx.x;
  if (i >= n4) return;
  float4 v = ((const float4*)in)[i];
  us4 o; o.x = f2bf(v.x); o.y = f2bf(v.y); o.z = f2bf(v.z); o.w = f2bf(v.w);
  ((us4*)out)[i] = o;
}

// ---------------------------------------------------------------------------
// gemm_bt core (m97 structure): C[m][n] = sum_k A[m][k]*B[n][k]
// 128x128 tile, BK=64, 256 threads = 4 waves (2x2), each wave 64x64 (4x4 frags).
// EPI=0: write bf16 to Cb.  EPI=1: write f32 + bias[n] to Cf.
// ---------------------------------------------------------------------------
template<int EPI>
__device__ __forceinline__ void gemm_core(
    const unsigned short* __restrict__ A, int lda,
    const unsigned short* __restrict__ Bm, int ldb,
    unsigned short* __restrict__ Cb, float* __restrict__ Cf, int ldc,
    const float* __restrict__ bias,
    int K, int m0, int n0) {
  __shared__ __align__(16) unsigned short lsA[128*64];
  __shared__ __align__(16) unsigned short lsB[128*64];
  const int tid    = threadIdx.x;
  const int w      = tid >> 6, l = tid & 63;
  const int lane15 = l & 15,  lgrp = l >> 4;
  const int wm     = (w >> 1) * 64, wn = (w & 1) * 64;
  const int srow   = l >> 3;          // staging: 8 rows per 1KB wave-load
  const int scol   = (l & 7) * 8;     // 8 bf16 per lane

  f32x4 acc[4][4] = {};

  for (int kt = 0; kt < K; kt += 64) {
    __syncthreads();                  // protect LDS from overwrite
    #pragma unroll
    for (int q = 0; q < 4; ++q) {
      const int blkrow = (w*4 + q) * 8;
      async16(A  + (size_t)(m0 + blkrow + srow) * lda + kt + scol, &lsA[(w*4+q)*512]);
      async16(Bm + (size_t)(n0 + blkrow + srow) * ldb + kt + scol, &lsB[(w*4+q)*512]);
    }
    __syncthreads();                  // compiler drains vmcnt(0) here -> tiles ready
    #pragma unroll
    for (int kk = 0; kk < 64; kk += 32) {
      bf16x8 aF[4], bF[4];
      #pragma unroll
      for (int mi = 0; mi < 4; ++mi)
        aF[mi] = *(const bf16x8*)&lsA[(wm + mi*16 + lane15)*64 + kk + lgrp*8];
      #pragma unroll
      for (int ni = 0; ni < 4; ++ni)
        bF[ni] = *(const bf16x8*)&lsB[(wn + ni*16 + lane15)*64 + kk + lgrp*8];
      #pragma unroll
      for (int mi = 0; mi < 4; ++mi)
        #pragma unroll
        for (int ni = 0; ni < 4; ++ni)
          acc[mi][ni] = __builtin_amdgcn_mfma_f32_16x16x32_bf16(aF[mi], bF[ni], acc[mi][ni], 0, 0, 0);
    }
  }

  if (EPI == 0) {
    #pragma unroll
    for (int mi = 0; mi < 4; ++mi)
      #pragma unroll
      for (int r = 0; r < 4; ++r) {
        const size_t mrow = (size_t)(m0 + wm + mi*16 + lgrp*4 + r);
        #pragma unroll
        for (int ni = 0; ni < 4; ++ni)
          Cb[mrow * ldc + n0 + wn + ni*16 + lane15] = f2bf(acc[mi][ni][r]);
      }
  } else {
    float bv[4];
    #pragma unroll
    for (int ni = 0; ni < 4; ++ni) bv[ni] = bias[n0 + wn + ni*16 + lane15];
    #pragma unroll
    for (int mi = 0; mi < 4; ++mi)
      #pragma unroll
      for (int r = 0; r < 4; ++r) {
        const size_t mrow = (size_t)(m0 + wm + mi*16 + lgrp*4 + r);
        #pragma unroll
        for (int ni = 0; ni < 4; ++ni)
          Cf[mrow * ldc + n0 + wn + ni*16 + lane15] = acc[mi][ni][r] + bv[ni];
      }
  }
}

// Stage 1: per b:  slots[ec][i] = sum_t maskT[ec][t] * xT[i][t]
// M=4096 (32 tiles), N=1024 (8 tiles), K=4096
__global__ __launch_bounds__(256) void gemm1_kernel(const unsigned short* __restrict__ maskT,
                                                    const unsigned short* __restrict__ xT,
                                                    unsigned short* __restrict__ slots) {
  const int bx = blockIdx.x;
  const int b  = bx >> 8;          // 256 tiles per b
  const int t  = bx & 255;
  const int tm = t & 31, tn = t >> 5;
  gemm_core<0>(maskT + (size_t)b*EC_*T_, T_,
               xT    + (size_t)b*I_*T_,  T_,
               slots + (size_t)b*EC_*I_, nullptr, I_,
               nullptr, T_, tm*128, tn*128);
}

// Stage 2: per (b,e):  out[c][o] = sum_i slots[c][i] * W[o][i] + bias[o]
// M=512 (4 tiles), N=1024 (8 tiles), K=1024
__global__ __launch_bounds__(256) void gemm2_kernel(const unsigned short* __restrict__ slots,
                                                    const unsigned short* __restrict__ wB,
                                                    const float* __restrict__ bias,
                                                    float* __restrict__ out) {
  const int bx = blockIdx.x;
  const int be = bx >> 5;          // 32 tiles per (b,e)
  const int e  = be & 7;
  const int t  = bx & 31;
  const int tm = t & 3, tn = t >> 2;
  gemm_core<1>(slots + (size_t)be*C_*I_, I_,
               wB    + (size_t)e*O_*I_,  I_,
               nullptr, out + (size_t)be*C_*O_, O_,
               bias + e*O_, I_, tm*128, tn*128);
}

// ---------------------------------------------------------------------------
extern "C" void kernel_launch(void* const* d_in, const int* in_sizes, int n_in,
                              void* d_out, int out_size, void* d_ws, size_t ws_size,
                              hipStream_t stream) {
  const float* x      = (const float*)d_in[0];   // [B,T,I]
  const float* mask   = (const float*)d_in[1];   // [B,T,E,C]
  const float* weight = (const float*)d_in[2];   // [E,O,I]
  const float* bias   = (const float*)d_in[3];   // [E,O]
  float* out = (float*)d_out;                    // [B,E,C,O]

  // Workspace layout (208 MB total):
  unsigned short* maskT = (unsigned short*)d_ws;                            // [B][EC][T] 134.2 MB
  unsigned short* xT    = (unsigned short*)((char*)d_ws + 134217728);       // [B][I][T]   33.6 MB
  unsigned short* wB    = (unsigned short*)((char*)d_ws + 167772160);       // [E][O][I]   16.8 MB
  unsigned short* slots = (unsigned short*)((char*)d_ws + 184549376);       // [B][EC][I]  33.6 MB

  tcast_kernel<T_, EC_><<<dim3(B_*(T_/64)*(EC_/64)), dim3(256), 0, stream>>>(mask, maskT);
  tcast_kernel<T_, I_ ><<<dim3(B_*(T_/64)*(I_/64)),  dim3(256), 0, stream>>>(x, xT);
  wcvt_kernel<<<dim3((E_*O_*I_/4 + 255)/256), dim3(256), 0, stream>>>(weight, wB, E_*O_*I_/4);
  gemm1_kernel<<<dim3(B_*32*8), dim3(256), 0, stream>>>(maskT, xT, slots);
  gemm2_kernel<<<dim3(B_*E_*4*8), dim3(256), 0, stream>>>(slots, wB, bias, out);
}

// Round 2
// 612.822 us; speedup vs baseline: 1.1827x; 1.1827x over previous
//
#include <hip/hip_runtime.h>
#include <stdint.h>
#include <stddef.h>

// Problem constants (ExpertsChooseMaskedContract)
#define B_  4
#define T_  4096
#define I_  1024
#define E_  8
#define C_  512
#define O_  1024
#define EC_ (E_*C_)   // 4096

typedef __attribute__((ext_vector_type(8))) short bf16x8;   // 8 bf16 = 4 VGPR
typedef __attribute__((ext_vector_type(4))) float f32x4;    // MFMA C/D
typedef __attribute__((ext_vector_type(4))) unsigned short us4;

__device__ __forceinline__ unsigned short f2bf(float f) {
  unsigned u = __builtin_bit_cast(unsigned, f);
  u += 0x7FFFu + ((u >> 16) & 1u);
  return (unsigned short)(u >> 16);
}

// async global->LDS, 16B/lane. LDS dest = wave-uniform base (HW adds lane*16).
__device__ __forceinline__ void async16(const unsigned short* g, unsigned short* l) {
  __builtin_amdgcn_global_load_lds((const __attribute__((address_space(1))) void*)g,
                                   (__attribute__((address_space(3))) void*)l, 16, 0, 0);
}

#define FENCE() asm volatile("" ::: "memory")
#define BAR()   do { FENCE(); __builtin_amdgcn_s_barrier(); FENCE(); } while (0)

// ---------------------------------------------------------------------------
// Transpose + cast: in[b][R][CC] f32 -> out[b][CC][R] bf16. 64x64 tiles.
// ---------------------------------------------------------------------------
template<int R, int CC>
__global__ __launch_bounds__(256) void tcast_kernel(const float* __restrict__ in,
                                                    unsigned short* __restrict__ out) {
  __shared__ float ls[64][68];
  const int tilesPerB = (R/64)*(CC/64);
  const int bx = blockIdx.x;
  const int b  = bx / tilesPerB;
  const int t  = bx % tilesPerB;
  const int tr = t / (CC/64);
  const int tc = t % (CC/64);
  const float* ib = in + (size_t)b * R * CC;
  unsigned short* ob = out + (size_t)b * R * CC;
  const int tid = threadIdx.x;
  const int rr  = tid >> 4;
  const int c4  = (tid & 15) * 4;
  #pragma unroll
  for (int p = 0; p < 4; ++p) {
    const int r = p * 16 + rr;
    float4 v = *(const float4*)&ib[(size_t)(tr*64 + r) * CC + tc*64 + c4];
    *(float4*)&ls[r][c4] = v;
  }
  __syncthreads();
  #pragma unroll
  for (int p = 0; p < 4; ++p) {
    const int c = p * 16 + rr;
    us4 o;
    o.x = f2bf(ls[c4+0][c]);
    o.y = f2bf(ls[c4+1][c]);
    o.z = f2bf(ls[c4+2][c]);
    o.w = f2bf(ls[c4+3][c]);
    *(us4*)&ob[(size_t)(tc*64 + c) * R + tr*64 + c4] = o;
  }
}

__global__ __launch_bounds__(256) void wcvt_kernel(const float* __restrict__ in,
                                                   unsigned short* __restrict__ out, int n4) {
  const int i = blockIdx.x * 256 + threadIdx.x;
  if (i >= n4) return;
  float4 v = ((const float4*)in)[i];
  us4 o; o.x = f2bf(v.x); o.y = f2bf(v.y); o.z = f2bf(v.z); o.w = f2bf(v.w);
  ((us4*)out)[i] = o;
}

// ---------------------------------------------------------------------------
// 256x256 tile, BK=64, 8-phase schedule (T2 swizzle + T3/T4 counted vmcnt +
// T5 setprio). 512 threads = 8 waves (2Mx4N), per-wave 128x64 output.
// C[m][n] = sum_k A[m][k]*B[n][k].  EPI=0: bf16 out. EPI=1: f32 + bias.
// ---------------------------------------------------------------------------
template<int EPI>
__device__ __forceinline__ void gemm_core(
    const unsigned short* __restrict__ A, int lda,
    const unsigned short* __restrict__ Bm, int ldb,
    unsigned short* __restrict__ Cb, float* __restrict__ Cf, int ldc,
    const float* __restrict__ bias, int K, int m0, int n0)
{
  __shared__ __align__(16) unsigned short lsA[2][256*64];   // 64 KiB
  __shared__ __align__(16) unsigned short lsB[2][256*64];   // 64 KiB

  const int tid  = threadIdx.x;
  const int w    = tid >> 6;        // wave 0..7
  const int l    = tid & 63;
  const int l15  = l & 15;
  const int lgrp = l >> 4;          // 0..3
  const int wm   = (w >> 2) << 7;   // 0,128
  const int wn   = (w & 3) << 6;    // 0,64,128,192

  // staging geometry: per half-tile (128 rows x 64 bf16), 2 issues/wave,
  // wave w + issue j covers rows j*64 + w*8 .. +7; source col pre-swizzled
  // so linear LDS dest + swizzled ds_read agree (rule 21).
  const int srow = (w << 3) + (l >> 3);           // 0..63
  const int scol = ((l & 7) ^ (l >> 3)) << 3;     // element col, XOR-swizzled
  const int swz  = (l & 7) << 4;                  // ds_read byte swizzle (row&7)<<4
  const int colK0 = (lgrp << 4) ^ swz;            // kk=0 byte col (bits 4-6)
  const int colK1 = colK0 ^ 64;                   // kk=1

  f32x4 acc[8][4] = {};
  bf16x8 aF[4][2], bF[4][2];

#define RD_A(buf, mi, kk) \
  (*(const bf16x8*)((const char*)&lsA[buf][0] + ((wm + ((mi)<<4) + l15) << 7) + ((kk) ? colK1 : colK0)))
#define RD_B(buf, ni, kk) \
  (*(const bf16x8*)((const char*)&lsB[buf][0] + ((wn + ((ni)<<4) + l15) << 7) + ((kk) ? colK1 : colK0)))

#define ST_HALF(dst, OP, ld, rbase, half, ktS) do { \
  async16((OP) + (size_t)((rbase) + ((half)<<7) + srow) * (ld) + (ktS) + scol, \
          &(dst)[((((half)<<7) + (w<<3)) << 6)]); \
  async16((OP) + (size_t)((rbase) + ((half)<<7) + 64 + srow) * (ld) + (ktS) + scol, \
          &(dst)[((((half)<<7) + 64 + (w<<3)) << 6)]); \
} while (0)

#define MM(miq, niq) do { \
  __builtin_amdgcn_s_setprio(1); \
  _Pragma("unroll") for (int mi = 0; mi < 4; ++mi) \
  _Pragma("unroll") for (int ni = 0; ni < 2; ++ni) \
  _Pragma("unroll") for (int kk = 0; kk < 2; ++kk) \
    acc[(miq)*4+mi][(niq)*2+ni] = __builtin_amdgcn_mfma_f32_16x16x32_bf16( \
        aF[mi][kk], bF[(niq)*2+ni][kk], acc[(miq)*4+mi][(niq)*2+ni], 0, 0, 0); \
  __builtin_amdgcn_s_setprio(0); \
} while (0)

#define WAITLDS() do { \
  asm volatile("s_waitcnt lgkmcnt(0)" ::: "memory"); \
  __builtin_amdgcn_sched_barrier(0); \
} while (0)

  // One K-tile (4 phases). buf = this tile's buffer. k1 = kt of tile t+1,
  // k2 = kt of tile t+2. Staging slots: each half staged >=1 barrier after
  // its last reader; vmcnt(4) once per tile guarantees tile t+1 landed.
#define TILE(buf, k1, k2) do { \
  /* P1: read A-lo, B-lo; stage A1(t+1) */ \
  _Pragma("unroll") for (int mi = 0; mi < 4; ++mi) { aF[mi][0] = RD_A(buf, mi, 0); aF[mi][1] = RD_A(buf, mi, 1); } \
  _Pragma("unroll") for (int ni = 0; ni < 2; ++ni) { bF[ni][0] = RD_B(buf, ni, 0); bF[ni][1] = RD_B(buf, ni, 1); } \
  ST_HALF(lsA[(buf)^1], A, lda, m0, 1, k1); \
  BAR(); WAITLDS(); \
  MM(0, 0); \
  BAR(); \
  /* P2: read B-hi; stage B1(t+1) */ \
  _Pragma("unroll") for (int ni = 2; ni < 4; ++ni) { bF[ni][0] = RD_B(buf, ni, 0); bF[ni][1] = RD_B(buf, ni, 1); } \
  ST_HALF(lsB[(buf)^1], Bm, ldb, n0, 1, k1); \
  BAR(); WAITLDS(); \
  MM(0, 1); \
  BAR(); \
  /* P3: read A-hi; stage B0(t+2) (B reads of this tile done at P2) */ \
  _Pragma("unroll") for (int mi = 0; mi < 4; ++mi) { aF[mi][0] = RD_A(buf, mi+4, 0); aF[mi][1] = RD_A(buf, mi+4, 1); } \
  ST_HALF(lsB[buf], Bm, ldb, n0, 0, k2); \
  BAR(); WAITLDS(); \
  MM(1, 0); \
  BAR(); \
  /* P4: stage A0(t+2) (A reads done at P3); counted drain */ \
  ST_HALF(lsA[buf], A, lda, m0, 0, k2); \
  BAR(); \
  MM(1, 1); \
  asm volatile("s_waitcnt vmcnt(4)" ::: "memory"); \
  BAR(); \
} while (0)

  const int nt = K >> 6;
  // Prologue: B0(0),A0(0),A1(0),B1(0),B0(1),A0(1); drain to last 2 halves.
  ST_HALF(lsB[0], Bm, ldb, n0, 0, 0);
  ST_HALF(lsA[0], A,  lda, m0, 0, 0);
  ST_HALF(lsA[0], A,  lda, m0, 1, 0);
  ST_HALF(lsB[0], Bm, ldb, n0, 1, 0);
  ST_HALF(lsB[1], Bm, ldb, n0, 0, 64);
  ST_HALF(lsA[1], A,  lda, m0, 0, 64);
  asm volatile("s_waitcnt vmcnt(4)" ::: "memory");
  BAR();

  for (int j = 0; j < (nt >> 1); ++j) {
    const int t0 = j << 1;
    const int k1 = (t0 + 1) << 6;
    const int k2 = (t0 + 2 < nt) ? (t0 + 2) << 6 : 0;   // clamped tail (unused data)
    const int k3 = (t0 + 3 < nt) ? (t0 + 3) << 6 : 0;
    TILE(0, k1, k2);
    TILE(1, k2, k3);
  }
  asm volatile("s_waitcnt vmcnt(0)" ::: "memory");

#undef TILE
#undef WAITLDS
#undef MM
#undef ST_HALF
#undef RD_B
#undef RD_A

  // Epilogue: C/D layout col=lane&15, row=(lane>>4)*4+reg (m89-verified).
  if (EPI == 0) {
    #pragma unroll
    for (int mi = 0; mi < 8; ++mi)
      #pragma unroll
      for (int r = 0; r < 4; ++r) {
        const size_t row = (size_t)(m0 + wm + mi*16 + lgrp*4 + r);
        #pragma unroll
        for (int ni = 0; ni < 4; ++ni)
          Cb[row * ldc + n0 + wn + ni*16 + l15] = f2bf(acc[mi][ni][r]);
      }
  } else {
    float bv[4];
    #pragma unroll
    for (int ni = 0; ni < 4; ++ni) bv[ni] = bias[n0 + wn + ni*16 + l15];
    #pragma unroll
    for (int mi = 0; mi < 8; ++mi)
      #pragma unroll
      for (int r = 0; r < 4; ++r) {
        const size_t row = (size_t)(m0 + wm + mi*16 + lgrp*4 + r);
        #pragma unroll
        for (int ni = 0; ni < 4; ++ni)
          Cf[row * ldc + n0 + wn + ni*16 + l15] = acc[mi][ni][r] + bv[ni];
      }
  }
}

// Stage 1: per b: slots[ec][i] = sum_t maskT[ec][t]*xT[i][t].
// M=4096 (16 tiles) x N=1024 (4 tiles) x 4 b = 256 blocks (1/CU).
// XCD-panel swizzle: the 4 n-tiles sharing an m-panel land on one XCD.
__global__ __launch_bounds__(512, 2) void gemm1_kernel(const unsigned short* __restrict__ maskT,
                                                       const unsigned short* __restrict__ xT,
                                                       unsigned short* __restrict__ slots) {
  const int wg  = blockIdx.x;          // 0..255
  const int xcd = wg & 7, s = wg >> 3; // s 0..31
  const int tn  = s & 3;
  const int p   = xcd * 8 + (s >> 2);  // panel 0..63
  const int b   = p >> 4, tm = p & 15;
  gemm_core<0>(maskT + (size_t)b*EC_*T_, T_,
               xT    + (size_t)b*I_*T_,  T_,
               slots + (size_t)b*EC_*I_, nullptr, I_,
               nullptr, T_, tm*256, tn*256);
}

// Stage 2: per (b,e): out[c][o] = sum_i slots[c][i]*W[o][i] + bias[o].
// M=512 (2) x N=1024 (4) x 32 (b,e) = 256 blocks (1/CU).
__global__ __launch_bounds__(512, 2) void gemm2_kernel(const unsigned short* __restrict__ slots,
                                                       const unsigned short* __restrict__ wB,
                                                       const float* __restrict__ bias,
                                                       float* __restrict__ out) {
  const int wg  = blockIdx.x;
  const int xcd = wg & 7, s = wg >> 3;     // s 0..31
  const int be  = xcd * 4 + (s >> 3);      // 0..31 (b,e) group per XCD
  const int e   = be & 7;
  const int tm  = (s >> 2) & 1, tn = s & 3;
  gemm_core<1>(slots + (size_t)be*C_*I_, I_,
               wB    + (size_t)e*O_*I_,  I_,
               nullptr, out + (size_t)be*C_*O_, O_,
               bias + e*O_, I_, tm*256, tn*256);
}

// ---------------------------------------------------------------------------
extern "C" void kernel_launch(void* const* d_in, const int* in_sizes, int n_in,
                              void* d_out, int out_size, void* d_ws, size_t ws_size,
                              hipStream_t stream) {
  const float* x      = (const float*)d_in[0];   // [B,T,I]
  const float* mask   = (const float*)d_in[1];   // [B,T,E,C]
  const float* weight = (const float*)d_in[2];   // [E,O,I]
  const float* bias   = (const float*)d_in[3];   // [E,O]
  float* out = (float*)d_out;                    // [B,E,C,O]

  unsigned short* maskT = (unsigned short*)d_ws;                            // [B][EC][T] 134.2 MB
  unsigned short* xT    = (unsigned short*)((char*)d_ws + 134217728);       // [B][I][T]   33.6 MB
  unsigned short* wB    = (unsigned short*)((char*)d_ws + 167772160);       // [E][O][I]   16.8 MB
  unsigned short* slots = (unsigned short*)((char*)d_ws + 184549376);       // [B][EC][I]  33.6 MB

  tcast_kernel<T_, EC_><<<dim3(B_*(T_/64)*(EC_/64)), dim3(256), 0, stream>>>(mask, maskT);
  tcast_kernel<T_, I_ ><<<dim3(B_*(T_/64)*(I_/64)),  dim3(256), 0, stream>>>(x, xT);
  wcvt_kernel<<<dim3((E_*O_*I_/4 + 255)/256), dim3(256), 0, stream>>>(weight, wB, E_*O_*I_/4);
  gemm1_kernel<<<dim3(256), dim3(512), 0, stream>>>(maskT, xT, slots);
  gemm2_kernel<<<dim3(256), dim3(512), 0, stream>>>(slots, wB, bias, out);
}

// Round 5
// 612.679 us; speedup vs baseline: 1.1830x; 1.0002x over previous
//
#include <hip/hip_runtime.h>
#include <stdint.h>
#include <stddef.h>

// Problem constants (ExpertsChooseMaskedContract)
#define B_  4
#define T_  4096
#define I_  1024
#define E_  8
#define C_  512
#define O_  1024
#define EC_ (E_*C_)   // 4096

typedef __attribute__((ext_vector_type(8))) short bf16x8;   // 8 bf16 = 4 VGPR
typedef __attribute__((ext_vector_type(4))) float f32x4;    // MFMA C/D
typedef __attribute__((ext_vector_type(4))) unsigned short us4;

__device__ __forceinline__ unsigned short f2bf(float f) {
  unsigned u = __builtin_bit_cast(unsigned, f);
  u += 0x7FFFu + ((u >> 16) & 1u);
  return (unsigned short)(u >> 16);
}

// async global->LDS, 16B/lane. LDS dest = wave-uniform base (HW adds lane*16).
__device__ __forceinline__ void async16(const unsigned short* g, unsigned short* l) {
  __builtin_amdgcn_global_load_lds((const __attribute__((address_space(1))) void*)g,
                                   (__attribute__((address_space(3))) void*)l, 16, 0, 0);
}

#define FENCE() asm volatile("" ::: "memory")
#define BAR()   do { FENCE(); __builtin_amdgcn_s_barrier(); FENCE(); } while (0)

// ---------------------------------------------------------------------------
// Transpose + cast: in[b][R][CC] f32 -> out[b][CC][R] bf16. 64x64 tiles.
// bf16-in-LDS with 8B-granule XOR swizzle g^=(row>>2)&15: both write and read
// phases are 2-way on banks (free, m136). LDS traffic halved vs f32 staging.
// ---------------------------------------------------------------------------
template<int R, int CC>
__global__ __launch_bounds__(256) void tcast_kernel(const float* __restrict__ in,
                                                    unsigned short* __restrict__ out) {
  __shared__ unsigned short ls[64*64];   // 8 KiB, granule-swizzled
  const int tilesPerB = (R/64)*(CC/64);
  const int bx = blockIdx.x;
  const int b  = bx / tilesPerB;
  const int t  = bx % tilesPerB;
  const int tr = t / (CC/64);
  const int tc = t % (CC/64);
  const float* ib = in + (size_t)b * R * CC;
  unsigned short* ob = out + (size_t)b * R * CC;
  const int tid = threadIdx.x;
  const int rr  = tid >> 4;          // 0..15
  const int g   = tid & 15;          // 8B granule (4 bf16)
  #pragma unroll
  for (int p = 0; p < 4; ++p) {
    const int r = p * 16 + rr;
    float4 v = *(const float4*)&ib[(size_t)(tr*64 + r) * CC + tc*64 + g*4];
    us4 o; o.x = f2bf(v.x); o.y = f2bf(v.y); o.z = f2bf(v.z); o.w = f2bf(v.w);
    *(us4*)&ls[r*64 + ((g ^ ((r >> 2) & 15)) << 2)] = o;
  }
  __syncthreads();
  #pragma unroll
  for (int p = 0; p < 4; ++p) {
    const int c = p * 16 + rr;       // input col = output row
    us4 o;
    #pragma unroll
    for (int j = 0; j < 4; ++j) {
      const int tt = g*4 + j;        // input row = output col
      o[j] = ls[tt*64 + (((c >> 2) ^ ((tt >> 2) & 15)) << 2) + (c & 3)];
    }
    *(us4*)&ob[(size_t)(tc*64 + c) * R + tr*64 + g*4] = o;
  }
}

__global__ __launch_bounds__(256) void wcvt_kernel(const float* __restrict__ in,
                                                   unsigned short* __restrict__ out, int n4) {
  const int i = blockIdx.x * 256 + threadIdx.x;
  if (i >= n4) return;
  float4 v = ((const float4*)in)[i];
  us4 o; o.x = f2bf(v.x); o.y = f2bf(v.y); o.z = f2bf(v.z); o.w = f2bf(v.w);
  ((us4*)out)[i] = o;
}

// ---------------------------------------------------------------------------
// 256x256 tile, BK=64, 8-phase schedule (T2 swizzle + T3/T4 counted vmcnt +
// T5 setprio). 512 threads = 8 waves (2Mx4N), per-wave 128x64 output.
// C[m][n] = sum_k A[m][k]*B[n][k].  EPI=0: bf16 out. EPI=1: f32 + bias.
// FROZEN from round 2 (verified race-free; ~m201 parity).
// ---------------------------------------------------------------------------
template<int EPI>
__device__ __forceinline__ void gemm_core(
    const unsigned short* __restrict__ A, int lda,
    const unsigned short* __restrict__ Bm, int ldb,
    unsigned short* __restrict__ Cb, float* __restrict__ Cf, int ldc,
    const float* __restrict__ bias, int K, int m0, int n0)
{
  __shared__ __align__(16) unsigned short lsA[2][256*64];   // 64 KiB
  __shared__ __align__(16) unsigned short lsB[2][256*64];   // 64 KiB

  const int tid  = threadIdx.x;
  const int w    = tid >> 6;        // wave 0..7
  const int l    = tid & 63;
  const int l15  = l & 15;
  const int lgrp = l >> 4;          // 0..3
  const int wm   = (w >> 2) << 7;   // 0,128
  const int wn   = (w & 3) << 6;    // 0,64,128,192

  // staging geometry: per half-tile (128 rows x 64 bf16), 2 issues/wave,
  // wave w + issue j covers rows j*64 + w*8 .. +7; source col pre-swizzled
  // so linear LDS dest + swizzled ds_read agree (rule 21).
  const int srow = (w << 3) + (l >> 3);           // 0..63
  const int scol = ((l & 7) ^ (l >> 3)) << 3;     // element col, XOR-swizzled
  const int swz  = (l & 7) << 4;                  // ds_read byte swizzle (row&7)<<4
  const int colK0 = (lgrp << 4) ^ swz;            // kk=0 byte col (bits 4-6)
  const int colK1 = colK0 ^ 64;                   // kk=1

  f32x4 acc[8][4] = {};
  bf16x8 aF[4][2], bF[4][2];

#define RD_A(buf, mi, kk) \
  (*(const bf16x8*)((const char*)&lsA[buf][0] + ((wm + ((mi)<<4) + l15) << 7) + ((kk) ? colK1 : colK0)))
#define RD_B(buf, ni, kk) \
  (*(const bf16x8*)((const char*)&lsB[buf][0] + ((wn + ((ni)<<4) + l15) << 7) + ((kk) ? colK1 : colK0)))

#define ST_HALF(dst, OP, ld, rbase, half, ktS) do { \
  async16((OP) + (size_t)((rbase) + ((half)<<7) + srow) * (ld) + (ktS) + scol, \
          &(dst)[((((half)<<7) + (w<<3)) << 6)]); \
  async16((OP) + (size_t)((rbase) + ((half)<<7) + 64 + srow) * (ld) + (ktS) + scol, \
          &(dst)[((((half)<<7) + 64 + (w<<3)) << 6)]); \
} while (0)

#define MM(miq, niq) do { \
  __builtin_amdgcn_s_setprio(1); \
  _Pragma("unroll") for (int mi = 0; mi < 4; ++mi) \
  _Pragma("unroll") for (int ni = 0; ni < 2; ++ni) \
  _Pragma("unroll") for (int kk = 0; kk < 2; ++kk) \
    acc[(miq)*4+mi][(niq)*2+ni] = __builtin_amdgcn_mfma_f32_16x16x32_bf16( \
        aF[mi][kk], bF[(niq)*2+ni][kk], acc[(miq)*4+mi][(niq)*2+ni], 0, 0, 0); \
  __builtin_amdgcn_s_setprio(0); \
} while (0)

#define WAITLDS() do { \
  asm volatile("s_waitcnt lgkmcnt(0)" ::: "memory"); \
  __builtin_amdgcn_sched_barrier(0); \
} while (0)

  // One K-tile (4 phases). buf = this tile's buffer. k1 = kt of tile t+1,
  // k2 = kt of tile t+2. Staging slots: each half staged >=1 barrier after
  // its last reader; vmcnt(4) once per tile guarantees tile t+1 landed.
#define TILE(buf, k1, k2) do { \
  /* P1: read A-lo, B-lo; stage A1(t+1) */ \
  _Pragma("unroll") for (int mi = 0; mi < 4; ++mi) { aF[mi][0] = RD_A(buf, mi, 0); aF[mi][1] = RD_A(buf, mi, 1); } \
  _Pragma("unroll") for (int ni = 0; ni < 2; ++ni) { bF[ni][0] = RD_B(buf, ni, 0); bF[ni][1] = RD_B(buf, ni, 1); } \
  ST_HALF(lsA[(buf)^1], A, lda, m0, 1, k1); \
  BAR(); WAITLDS(); \
  MM(0, 0); \
  BAR(); \
  /* P2: read B-hi; stage B1(t+1) */ \
  _Pragma("unroll") for (int ni = 2; ni < 4; ++ni) { bF[ni][0] = RD_B(buf, ni, 0); bF[ni][1] = RD_B(buf, ni, 1); } \
  ST_HALF(lsB[(buf)^1], Bm, ldb, n0, 1, k1); \
  BAR(); WAITLDS(); \
  MM(0, 1); \
  BAR(); \
  /* P3: read A-hi; stage B0(t+2) (B reads of this tile done at P2) */ \
  _Pragma("unroll") for (int mi = 0; mi < 4; ++mi) { aF[mi][0] = RD_A(buf, mi+4, 0); aF[mi][1] = RD_A(buf, mi+4, 1); } \
  ST_HALF(lsB[buf], Bm, ldb, n0, 0, k2); \
  BAR(); WAITLDS(); \
  MM(1, 0); \
  BAR(); \
  /* P4: stage A0(t+2) (A reads done at P3); counted drain */ \
  ST_HALF(lsA[buf], A, lda, m0, 0, k2); \
  BAR(); \
  MM(1, 1); \
  asm volatile("s_waitcnt vmcnt(4)" ::: "memory"); \
  BAR(); \
} while (0)

  const int nt = K >> 6;
  // Prologue: B0(0),A0(0),A1(0),B1(0),B0(1),A0(1); drain to last 2 halves.
  ST_HALF(lsB[0], Bm, ldb, n0, 0, 0);
  ST_HALF(lsA[0], A,  lda, m0, 0, 0);
  ST_HALF(lsA[0], A,  lda, m0, 1, 0);
  ST_HALF(lsB[0], Bm, ldb, n0, 1, 0);
  ST_HALF(lsB[1], Bm, ldb, n0, 0, 64);
  ST_HALF(lsA[1], A,  lda, m0, 0, 64);
  asm volatile("s_waitcnt vmcnt(4)" ::: "memory");
  BAR();

  for (int j = 0; j < (nt >> 1); ++j) {
    const int t0 = j << 1;
    const int k1 = (t0 + 1) << 6;
    const int k2 = (t0 + 2 < nt) ? (t0 + 2) << 6 : 0;   // clamped tail (unused data)
    const int k3 = (t0 + 3 < nt) ? (t0 + 3) << 6 : 0;
    TILE(0, k1, k2);
    TILE(1, k2, k3);
  }
  asm volatile("s_waitcnt vmcnt(0)" ::: "memory");

#undef TILE
#undef WAITLDS
#undef MM
#undef ST_HALF
#undef RD_B
#undef RD_A

  // Epilogue: C/D layout col=lane&15, row=(lane>>4)*4+reg (m89-verified).
  if (EPI == 0) {
    #pragma unroll
    for (int mi = 0; mi < 8; ++mi)
      #pragma unroll
      for (int r = 0; r < 4; ++r) {
        const size_t row = (size_t)(m0 + wm + mi*16 + lgrp*4 + r);
        #pragma unroll
        for (int ni = 0; ni < 4; ++ni)
          Cb[row * ldc + n0 + wn + ni*16 + l15] = f2bf(acc[mi][ni][r]);
      }
  } else {
    float bv[4];
    #pragma unroll
    for (int ni = 0; ni < 4; ++ni) bv[ni] = bias[n0 + wn + ni*16 + l15];
    #pragma unroll
    for (int mi = 0; mi < 8; ++mi)
      #pragma unroll
      for (int r = 0; r < 4; ++r) {
        const size_t row = (size_t)(m0 + wm + mi*16 + lgrp*4 + r);
        #pragma unroll
        for (int ni = 0; ni < 4; ++ni)
          Cf[row * ldc + n0 + wn + ni*16 + l15] = acc[mi][ni][r] + bv[ni];
      }
  }
}

// Stage 1: per b: slots[ec][i] = sum_t maskT[ec][t]*xT[i][t].
// M=4096 (16 tiles) x N=1024 (4 tiles) x 4 b = 256 blocks (1/CU).
// XCD-panel swizzle: the 4 n-tiles sharing an m-panel land on one XCD.
__global__ __launch_bounds__(512, 2) void gemm1_kernel(const unsigned short* __restrict__ maskT,
                                                       const unsigned short* __restrict__ xT,
                                                       unsigned short* __restrict__ slots) {
  const int wg  = blockIdx.x;          // 0..255
  const int xcd = wg & 7, s = wg >> 3; // s 0..31
  const int tn  = s & 3;
  const int p   = xcd * 8 + (s >> 2);  // panel 0..63
  const int b   = p >> 4, tm = p & 15;
  gemm_core<0>(maskT + (size_t)b*EC_*T_, T_,
               xT    + (size_t)b*I_*T_,  T_,
               slots + (size_t)b*EC_*I_, nullptr, I_,
               nullptr, T_, tm*256, tn*256);
}

// Stage 2: per (b,e): out[c][o] = sum_i slots[c][i]*W[o][i] + bias[o].
// M=512 (2) x N=1024 (4) x 32 (b,e) = 256 blocks (1/CU).
__global__ __launch_bounds__(512, 2) void gemm2_kernel(const unsigned short* __restrict__ slots,
                                                       const unsigned short* __restrict__ wB,
                                                       const float* __restrict__ bias,
                                                       float* __restrict__ out) {
  const int wg  = blockIdx.x;
  const int xcd = wg & 7, s = wg >> 3;     // s 0..31
  const int be  = xcd * 4 + (s >> 3);      // 0..31 (b,e) group per XCD
  const int e   = be & 7;
  const int tm  = (s >> 2) & 1, tn = s & 3;
  gemm_core<1>(slots + (size_t)be*C_*I_, I_,
               wB    + (size_t)e*O_*I_,  I_,
               nullptr, out + (size_t)be*C_*O_, O_,
               bias + e*O_, I_, tm*256, tn*256);
}

// ---------------------------------------------------------------------------
extern "C" void kernel_launch(void* const* d_in, const int* in_sizes, int n_in,
                              void* d_out, int out_size, void* d_ws, size_t ws_size,
                              hipStream_t stream) {
  const float* x      = (const float*)d_in[0];   // [B,T,I]
  const float* mask   = (const float*)d_in[1];   // [B,T,E,C]
  const float* weight = (const float*)d_in[2];   // [E,O,I]
  const float* bias   = (const float*)d_in[3];   // [E,O]
  float* out = (float*)d_out;                    // [B,E,C,O]

  unsigned short* maskT = (unsigned short*)d_ws;                            // [B][EC][T] 134.2 MB
  unsigned short* xT    = (unsigned short*)((char*)d_ws + 134217728);       // [B][I][T]   33.6 MB
  unsigned short* wB    = (unsigned short*)((char*)d_ws + 167772160);       // [E][O][I]   16.8 MB
  unsigned short* slots = (unsigned short*)((char*)d_ws + 184549376);       // [B][EC][I]  33.6 MB

  tcast_kernel<T_, EC_><<<dim3(B_*(T_/64)*(EC_/64)), dim3(256), 0, stream>>>(mask, maskT);
  tcast_kernel<T_, I_ ><<<dim3(B_*(T_/64)*(I_/64)),  dim3(256), 0, stream>>>(x, xT);
  wcvt_kernel<<<dim3((E_*O_*I_/4 + 255)/256), dim3(256), 0, stream>>>(weight, wB, E_*O_*I_/4);
  gemm1_kernel<<<dim3(256), dim3(512), 0, stream>>>(maskT, xT, slots);
  gemm2_kernel<<<dim3(256), dim3(512), 0, stream>>>(slots, wB, bias, out);
}